// Round 2
// baseline (3631.966 us; speedup 1.0000x reference)
//
#include <hip/hip_runtime.h>
#include <math.h>

#define Bn 8
#define Ln 2048
#define DIMn 768
#define DIN 1536           // D_INNER
#define DSTATE 16
#define DTRANK 48
#define XPN 80             // DT_RANK + 2*D_STATE
#define NR (Bn*Ln)         // 16384 rows

typedef unsigned short bf16_t;

__device__ __forceinline__ float sigf(float v){ return 1.0f/(1.0f+__expf(-v)); }

__device__ __forceinline__ float bf2f(unsigned short u){
    return __uint_as_float(((unsigned int)u) << 16);
}
__device__ __forceinline__ unsigned short f2bf(float f){
    unsigned int x = __float_as_uint(f);
    unsigned int r = (x + 0x7FFFu + ((x >> 16) & 1u)) >> 16;
    return (unsigned short)r;
}

// ---------------- LayerNorm + mask (writes xn into d_out region) ----------------
__global__ __launch_bounds__(256) void ln_kernel(
    const float* __restrict__ x, const int* __restrict__ mask,
    const float* __restrict__ g, const float* __restrict__ bta,
    float* __restrict__ xn)
{
    int row = blockIdx.x;
    int t = threadIdx.x;
    const float* xr = x + (size_t)row * DIMn;
    float v0 = xr[t], v1 = xr[t+256], v2 = xr[t+512];
    float s  = v0+v1+v2;
    float sq = v0*v0+v1*v1+v2*v2;
    #pragma unroll
    for (int off = 32; off; off >>= 1) {
        s  += __shfl_down(s,  off, 64);
        sq += __shfl_down(sq, off, 64);
    }
    __shared__ float ls[4], lq[4];
    int wave = t >> 6, lane = t & 63;
    if (lane == 0) { ls[wave] = s; lq[wave] = sq; }
    __syncthreads();
    s  = ls[0]+ls[1]+ls[2]+ls[3];
    sq = lq[0]+lq[1]+lq[2]+lq[3];
    float mu  = s * (1.0f/DIMn);
    float var = sq * (1.0f/DIMn) - mu*mu;
    float rstd = rsqrtf(var + 1e-5f);
    float mf = (float)mask[row];
    float* o = xn + (size_t)row * DIMn;
    o[t]     = ((v0-mu)*rstd*g[t]     + bta[t])     * mf;
    o[t+256] = ((v1-mu)*rstd*g[t+256] + bta[t+256]) * mf;
    o[t+512] = ((v2-mu)*rstd*g[t+512] + bta[t+512]) * mf;
}

// ---- typed helpers: A-tile load (4 elems -> f32), C store (4 f32 -> TC) ----
__device__ __forceinline__ void ldA4(const float* p, float v[4]) {
    float4 t = *(const float4*)p; v[0]=t.x; v[1]=t.y; v[2]=t.z; v[3]=t.w;
}
__device__ __forceinline__ void ldA4(const bf16_t* p, float v[4]) {
    ushort4 t = *(const ushort4*)p;
    v[0]=bf2f(t.x); v[1]=bf2f(t.y); v[2]=bf2f(t.z); v[3]=bf2f(t.w);
}
__device__ __forceinline__ void stC4(float* p, const float v[4]) {
    *(float4*)p = make_float4(v[0],v[1],v[2],v[3]);
}
__device__ __forceinline__ void stC4(bf16_t* p, const float v[4]) {
    ushort4 t; t.x=f2bf(v[0]); t.y=f2bf(v[1]); t.z=f2bf(v[2]); t.w=f2bf(v[3]);
    *(ushort4*)p = t;
}

// ---------------- Generic GEMM: C[M,N] = A[M,K] @ W[N,K]^T ----------------
// EPI: 0 = plain, 1 = softplus(acc + bias[n]), 2 = mf*(resid + acc)
template<typename TA, typename TC, int EPI>
__global__ __launch_bounds__(256) void gemm_kernel(
    const TA* __restrict__ A, int lda,
    const float* __restrict__ W,
    TC* __restrict__ C, int ldc,
    int N, int K,
    const float* __restrict__ bias,
    const float* __restrict__ resid,
    const int* __restrict__ mask)
{
    __shared__ float As[16][64];
    __shared__ float Ws[16][64];
    int m0 = blockIdx.y * 64;
    int n0 = blockIdx.x * 64;
    int t  = threadIdx.x;
    int lr = t >> 2;            // 0..63
    int lc = (t & 3) * 4;       // 0,4,8,12
    int tx = t & 15, ty = t >> 4;
    float acc[4][4] = {};

    for (int k0 = 0; k0 < K; k0 += 16) {
        float av[4];
        ldA4(A + (size_t)(m0+lr)*lda + k0 + lc, av);
        float wv[4] = {0.f,0.f,0.f,0.f};
        if (n0 + lr < N) {
            float4 w4 = *(const float4*)(W + (size_t)(n0+lr)*K + k0 + lc);
            wv[0]=w4.x; wv[1]=w4.y; wv[2]=w4.z; wv[3]=w4.w;
        }
        __syncthreads();
        As[lc+0][lr]=av[0]; As[lc+1][lr]=av[1]; As[lc+2][lr]=av[2]; As[lc+3][lr]=av[3];
        Ws[lc+0][lr]=wv[0]; Ws[lc+1][lr]=wv[1]; Ws[lc+2][lr]=wv[2]; Ws[lc+3][lr]=wv[3];
        __syncthreads();
        #pragma unroll
        for (int kk = 0; kk < 16; kk++) {
            const float4 a4 = *(const float4*)&As[kk][ty*4];
            const float4 w4 = *(const float4*)&Ws[kk][tx*4];
            float a[4] = {a4.x,a4.y,a4.z,a4.w};
            float w[4] = {w4.x,w4.y,w4.z,w4.w};
            #pragma unroll
            for (int i = 0; i < 4; i++)
                #pragma unroll
                for (int j = 0; j < 4; j++)
                    acc[i][j] = fmaf(a[i], w[j], acc[i][j]);
        }
    }

    int ncol = n0 + tx*4;
    if (ncol >= N) return;
    #pragma unroll
    for (int i = 0; i < 4; i++) {
        int row = m0 + ty*4 + i;
        TC* cp = C + (size_t)row*ldc + ncol;
        float v[4];
        if (EPI == 0) {
            v[0]=acc[i][0]; v[1]=acc[i][1]; v[2]=acc[i][2]; v[3]=acc[i][3];
        } else if (EPI == 1) {
            #pragma unroll
            for (int j = 0; j < 4; j++) {
                float u = acc[i][j] + bias[ncol+j];
                v[j] = (u > 20.f) ? u : log1pf(__expf(u));
            }
        } else {
            float mf = (float)mask[row];
            const float* rp = resid + (size_t)row*ldc + ncol;
            #pragma unroll
            for (int j = 0; j < 4; j++)
                v[j] = mf * (rp[j] + acc[i][j]);
        }
        stC4(cp, v);
    }
}

// ---------------- depthwise causal conv (width 4) + SiLU ----------------
__global__ __launch_bounds__(256) void conv_silu_kernel(
    const bf16_t* __restrict__ xz,    // (NR, 2*DIN); x_in = cols [0,DIN)
    const float* __restrict__ cw,     // (DIN, 4)
    const float* __restrict__ cb,
    bf16_t* __restrict__ xc)          // (NR, DIN)
{
    int idx = blockIdx.x*256 + threadIdx.x;
    int d = idx % DIN;
    int r = idx / DIN;
    int l = r % Ln;
    const float* w = cw + d*4;
    float acc = cb[d];
    #pragma unroll
    for (int j = 0; j < 4; j++) {
        int ll = l - 3 + j;
        if (ll >= 0) acc += bf2f(xz[((size_t)(r-3+j))*(2*DIN) + d]) * w[j];
    }
    float o = acc * sigf(acc);
    xc[(size_t)r*DIN + d] = f2bf(o);
}

// ---------------- selective scan + skip + gate ----------------
// thread = (b, d, s); 16 lanes per channel; yg written in-place over dt buffer
__global__ __launch_bounds__(256) void scan_kernel(
    bf16_t* __restrict__ dt_yg,       // (NR, DIN) in: dt, out: gated y
    const bf16_t* __restrict__ xc,    // (NR, DIN)
    const float* __restrict__ xdbl,   // (NR, 80): [.,48:64]=B, [.,64:80]=C
    const bf16_t* __restrict__ xz,    // (NR, 2*DIN): z = cols [DIN, 2*DIN)
    const float* __restrict__ A_log,  // (DIN, 16)
    const float* __restrict__ Dp)     // (DIN)
{
    int t  = threadIdx.x;
    int s  = t & 15;
    int dl = t >> 4;                   // 0..15
    int blk = blockIdx.x;              // 0..767
    int b  = blk / (DIN/16);
    int dg = blk % (DIN/16);
    int d  = dg*16 + dl;
    float Aval = -__expf(A_log[d*DSTATE + s]);
    float Dv = Dp[d];
    float h = 0.f;
    size_t rbase = (size_t)b * Ln;
    for (int l = 0; l < Ln; l++) {
        size_t row = rbase + l;
        float dtv = bf2f(dt_yg[row*DIN + d]);
        float xv  = bf2f(xc[row*DIN + d]);
        float Bv  = xdbl[row*XPN + DTRANK + s];
        float Cv  = xdbl[row*XPN + DTRANK + DSTATE + s];
        h = __expf(dtv*Aval)*h + dtv*xv*Bv;
        float p = h*Cv;
        p += __shfl_xor(p, 1, 64);
        p += __shfl_xor(p, 2, 64);
        p += __shfl_xor(p, 4, 64);
        p += __shfl_xor(p, 8, 64);
        if (s == 0) {
            float y = p + xv*Dv;
            float zv = bf2f(xz[row*(2*DIN) + DIN + d]);
            dt_yg[row*DIN + d] = f2bf(y * zv * sigf(zv));
        }
    }
}

extern "C" void kernel_launch(void* const* d_in, const int* in_sizes, int n_in,
                              void* d_out, int out_size, void* d_ws, size_t ws_size,
                              hipStream_t stream) {
    const float* x      = (const float*)d_in[0];
    const int*   mask   = (const int*)  d_in[1];
    const float* ln_g   = (const float*)d_in[2];
    const float* ln_b   = (const float*)d_in[3];
    const float* W_in   = (const float*)d_in[4];
    const float* conv_w = (const float*)d_in[5];
    const float* conv_b = (const float*)d_in[6];
    const float* W_xp   = (const float*)d_in[7];
    const float* W_dt   = (const float*)d_in[8];
    const float* b_dt   = (const float*)d_in[9];
    const float* A_log  = (const float*)d_in[10];
    const float* Dp     = (const float*)d_in[11];
    const float* W_out  = (const float*)d_in[12];
    float* out = (float*)d_out;

    // xn reuses d_out (consumed by in_proj before out_proj writes out).
    float* xn = out;

    // Workspace layout (207 MB total):
    char* wsb = (char*)d_ws;
    bf16_t* xz   = (bf16_t*)wsb;                          // NR*3072 bf16 = 100.7 MB
    bf16_t* xc   = (bf16_t*)(wsb + (size_t)NR*3072*2);    // NR*1536 bf16 =  50.3 MB
    float*  xdbl = (float*) (wsb + (size_t)NR*3072*2 + (size_t)NR*1536*2);          // NR*80 f32 = 5.2 MB
    bf16_t* dtb  = (bf16_t*)(wsb + (size_t)NR*3072*2 + (size_t)NR*1536*2 + (size_t)NR*XPN*4); // NR*1536 bf16 = 50.3 MB

    // 1. LayerNorm + mask -> xn (in d_out)
    ln_kernel<<<NR, 256, 0, stream>>>(x, mask, ln_g, ln_b, xn);

    // 2. in_proj: xz = xn @ W_in^T   (M=16384, N=3072, K=768)
    gemm_kernel<float, bf16_t, 0><<<dim3(3072/64, NR/64), 256, 0, stream>>>(
        xn, DIMn, W_in, xz, 2*DIN, 2*DIN, DIMn, nullptr, nullptr, nullptr);

    // 3. depthwise conv + SiLU -> xc
    conv_silu_kernel<<<(NR*DIN)/256, 256, 0, stream>>>(xz, conv_w, conv_b, xc);

    // 4. x_proj: xdbl = xc @ W_xp^T  (N=80, K=1536)
    gemm_kernel<bf16_t, float, 0><<<dim3((XPN+63)/64, NR/64), 256, 0, stream>>>(
        xc, DIN, W_xp, xdbl, XPN, XPN, DIN, nullptr, nullptr, nullptr);

    // 5. dt = softplus(dt_in @ W_dt^T + b_dt)  (N=1536, K=48)
    gemm_kernel<float, bf16_t, 1><<<dim3(DIN/64, NR/64), 256, 0, stream>>>(
        xdbl, XPN, W_dt, dtb, DIN, DIN, DTRANK, b_dt, nullptr, nullptr);

    // 6. selective scan + D-skip + SiLU gate (yg overwrites dtb)
    scan_kernel<<<Bn*(DIN/16), 256, 0, stream>>>(dtb, xc, xdbl, xz, A_log, Dp);

    // 7. out_proj + residual: out = mf*(x + yg @ W_out^T)  (N=768, K=1536)
    gemm_kernel<bf16_t, float, 2><<<dim3(DIMn/64, NR/64), 256, 0, stream>>>(
        dtb, DIN, W_out, out, DIMn, DIMn, DIN, nullptr, x, mask);
}

// Round 3
// 1343.758 us; speedup vs baseline: 2.7028x; 2.7028x over previous
//
#include <hip/hip_runtime.h>
#include <math.h>

#define Bn 8
#define Ln 2048
#define DIMn 768
#define DIN 1536           // D_INNER
#define DSTATE 16
#define DTRANK 48
#define XPN 80             // DT_RANK + 2*D_STATE
#define NR (Bn*Ln)         // 16384 rows

typedef unsigned short bf16_t;
typedef __attribute__((ext_vector_type(8))) short short8;   // 8 bf16 (4 VGPR)
typedef __attribute__((ext_vector_type(4))) float f32x4;

__device__ __forceinline__ float sigf(float v){ return 1.0f/(1.0f+__expf(-v)); }
__device__ __forceinline__ float bf2f(unsigned short u){
    return __uint_as_float(((unsigned int)u) << 16);
}
__device__ __forceinline__ unsigned short f2bf(float f){
    unsigned int x = __float_as_uint(f);
    unsigned int r = (x + 0x7FFFu + ((x >> 16) & 1u)) >> 16;
    return (unsigned short)r;
}

// ---------------- f32 -> bf16 weight conversion ----------------
__global__ __launch_bounds__(256) void f2bf_kernel(
    const float* __restrict__ in, bf16_t* __restrict__ out, int n)
{
    int i = blockIdx.x*256 + threadIdx.x;
    if (i < n) out[i] = f2bf(in[i]);
}

// ---------------- LayerNorm + mask -> bf16 ----------------
__global__ __launch_bounds__(256) void ln_kernel(
    const float* __restrict__ x, const int* __restrict__ mask,
    const float* __restrict__ g, const float* __restrict__ bta,
    bf16_t* __restrict__ xn)
{
    int row = blockIdx.x;
    int t = threadIdx.x;
    const float* xr = x + (size_t)row * DIMn;
    float v0 = xr[t], v1 = xr[t+256], v2 = xr[t+512];
    float s  = v0+v1+v2;
    float sq = v0*v0+v1*v1+v2*v2;
    #pragma unroll
    for (int off = 32; off; off >>= 1) {
        s  += __shfl_down(s,  off, 64);
        sq += __shfl_down(sq, off, 64);
    }
    __shared__ float ls[4], lq[4];
    int wave = t >> 6, lane = t & 63;
    if (lane == 0) { ls[wave] = s; lq[wave] = sq; }
    __syncthreads();
    s  = ls[0]+ls[1]+ls[2]+ls[3];
    sq = lq[0]+lq[1]+lq[2]+lq[3];
    float mu  = s * (1.0f/DIMn);
    float var = sq * (1.0f/DIMn) - mu*mu;
    float rstd = rsqrtf(var + 1e-5f);
    float mf = (float)mask[row];
    bf16_t* o = xn + (size_t)row * DIMn;
    o[t]     = f2bf(((v0-mu)*rstd*g[t]     + bta[t])     * mf);
    o[t+256] = f2bf(((v1-mu)*rstd*g[t+256] + bta[t+256]) * mf);
    o[t+512] = f2bf(((v2-mu)*rstd*g[t+512] + bta[t+512]) * mf);
}

// ---------------- bf16 MFMA GEMM: C[M,N] = A[M,K] @ W[N,K]^T ----------------
// 128x128 block tile, 4 waves (2x2), each wave 64x64 via 4x4 mfma 16x16x32 tiles.
// Fragments loaded directly from global (row-major in K => contiguous 16B).
// EPI: 0 = store bf16, 2 = f32 mf*(resid + acc)
template<int EPI, typename TC>
__global__ __launch_bounds__(256) void mfma_gemm(
    const bf16_t* __restrict__ A, int lda,
    const bf16_t* __restrict__ W,
    TC* __restrict__ C, int ldc, int K,
    const float* __restrict__ resid, const int* __restrict__ mask)
{
    int wave = threadIdx.x >> 6, lane = threadIdx.x & 63;
    int m0 = blockIdx.y*128 + (wave>>1)*64;
    int n0 = blockIdx.x*128 + (wave&1)*64;
    int lr = lane & 15;
    int ko = (lane>>4)*8;
    const bf16_t* Ap = A + (size_t)(m0+lr)*lda + ko;
    const bf16_t* Wp = W + (size_t)(n0+lr)*K   + ko;
    f32x4 acc[4][4] = {};

    for (int k0 = 0; k0 < K; k0 += 32) {
        short8 a[4], b[4];
        #pragma unroll
        for (int i = 0; i < 4; i++)
            a[i] = *(const short8*)(Ap + (size_t)i*16*lda + k0);
        #pragma unroll
        for (int i = 0; i < 4; i++)
            b[i] = *(const short8*)(Wp + (size_t)i*16*K + k0);
        #pragma unroll
        for (int mt = 0; mt < 4; mt++)
            #pragma unroll
            for (int nt = 0; nt < 4; nt++)
                acc[mt][nt] = __builtin_amdgcn_mfma_f32_16x16x32_bf16(
                    a[mt], b[nt], acc[mt][nt], 0, 0, 0);
    }

    int rb = (lane>>4)*4;
    #pragma unroll
    for (int mt = 0; mt < 4; mt++) {
        #pragma unroll
        for (int nt = 0; nt < 4; nt++) {
            int col = n0 + nt*16 + lr;
            #pragma unroll
            for (int r = 0; r < 4; r++) {
                int row = m0 + mt*16 + rb + r;
                float v = acc[mt][nt][r];
                if (EPI == 2)
                    v = (float)mask[row] * (resid[(size_t)row*ldc + col] + v);
                if constexpr (sizeof(TC) == 2)
                    C[(size_t)row*ldc + col] = f2bf(v);
                else
                    C[(size_t)row*ldc + col] = v;
            }
        }
    }
}

// ---- typed helpers for the small f32 GEMM ----
__device__ __forceinline__ void ldA4(const float* p, float v[4]) {
    float4 t = *(const float4*)p; v[0]=t.x; v[1]=t.y; v[2]=t.z; v[3]=t.w;
}
__device__ __forceinline__ void ldA4(const bf16_t* p, float v[4]) {
    ushort4 t = *(const ushort4*)p;
    v[0]=bf2f(t.x); v[1]=bf2f(t.y); v[2]=bf2f(t.z); v[3]=bf2f(t.w);
}
__device__ __forceinline__ void stC4(float* p, const float v[4]) {
    *(float4*)p = make_float4(v[0],v[1],v[2],v[3]);
}
__device__ __forceinline__ void stC4(bf16_t* p, const float v[4]) {
    ushort4 t; t.x=f2bf(v[0]); t.y=f2bf(v[1]); t.z=f2bf(v[2]); t.w=f2bf(v[3]);
    *(ushort4*)p = t;
}

// ---------------- small f32 GEMM (x_proj, dt_proj): C = A @ W^T ----------------
// EPI: 0 = plain f32, 1 = softplus(acc + bias[n]) -> bf16
template<typename TA, typename TC, int EPI>
__global__ __launch_bounds__(256) void gemm_kernel(
    const TA* __restrict__ A, int lda,
    const float* __restrict__ W,
    TC* __restrict__ C, int ldc,
    int N, int K,
    const float* __restrict__ bias)
{
    __shared__ float As[16][64];
    __shared__ float Ws[16][64];
    int m0 = blockIdx.y * 64;
    int n0 = blockIdx.x * 64;
    int t  = threadIdx.x;
    int lr = t >> 2;
    int lc = (t & 3) * 4;
    int tx = t & 15, ty = t >> 4;
    float acc[4][4] = {};

    for (int k0 = 0; k0 < K; k0 += 16) {
        float av[4];
        ldA4(A + (size_t)(m0+lr)*lda + k0 + lc, av);
        float wv[4] = {0.f,0.f,0.f,0.f};
        if (n0 + lr < N) {
            float4 w4 = *(const float4*)(W + (size_t)(n0+lr)*K + k0 + lc);
            wv[0]=w4.x; wv[1]=w4.y; wv[2]=w4.z; wv[3]=w4.w;
        }
        __syncthreads();
        As[lc+0][lr]=av[0]; As[lc+1][lr]=av[1]; As[lc+2][lr]=av[2]; As[lc+3][lr]=av[3];
        Ws[lc+0][lr]=wv[0]; Ws[lc+1][lr]=wv[1]; Ws[lc+2][lr]=wv[2]; Ws[lc+3][lr]=wv[3];
        __syncthreads();
        #pragma unroll
        for (int kk = 0; kk < 16; kk++) {
            const float4 a4 = *(const float4*)&As[kk][ty*4];
            const float4 w4 = *(const float4*)&Ws[kk][tx*4];
            float a[4] = {a4.x,a4.y,a4.z,a4.w};
            float w[4] = {w4.x,w4.y,w4.z,w4.w};
            #pragma unroll
            for (int i = 0; i < 4; i++)
                #pragma unroll
                for (int j = 0; j < 4; j++)
                    acc[i][j] = fmaf(a[i], w[j], acc[i][j]);
        }
    }

    int ncol = n0 + tx*4;
    if (ncol >= N) return;
    #pragma unroll
    for (int i = 0; i < 4; i++) {
        int row = m0 + ty*4 + i;
        TC* cp = C + (size_t)row*ldc + ncol;
        float v[4];
        if (EPI == 0) {
            v[0]=acc[i][0]; v[1]=acc[i][1]; v[2]=acc[i][2]; v[3]=acc[i][3];
        } else {
            #pragma unroll
            for (int j = 0; j < 4; j++) {
                float u = acc[i][j] + bias[ncol+j];
                v[j] = (u > 20.f) ? u : log1pf(__expf(u));
            }
        }
        stC4(cp, v);
    }
}

// ---------------- depthwise causal conv (width 4) + SiLU ----------------
__global__ __launch_bounds__(256) void conv_silu_kernel(
    const bf16_t* __restrict__ xz,
    const float* __restrict__ cw,
    const float* __restrict__ cb,
    bf16_t* __restrict__ xc)
{
    int idx = blockIdx.x*256 + threadIdx.x;
    int d = idx % DIN;
    int r = idx / DIN;
    int l = r % Ln;
    const float* w = cw + d*4;
    float acc = cb[d];
    #pragma unroll
    for (int j = 0; j < 4; j++) {
        int ll = l - 3 + j;
        if (ll >= 0) acc += bf2f(xz[((size_t)(r-3+j))*(2*DIN) + d]) * w[j];
    }
    float o = acc * sigf(acc);
    xc[(size_t)r*DIN + d] = f2bf(o);
}

// ---------------- selective scan, LDS-tiled ----------------
// block = (b, 16 channels); lane (c = t>>4, s = t&15); L tiled by 64.
// y (gated) written into the dead x_in half of xz (cols [0,DIN)).
__global__ __launch_bounds__(256) void scan_kernel(
    const bf16_t* __restrict__ dtb,   // (NR, DIN)  dt
    const bf16_t* __restrict__ xcb,   // (NR, DIN)  conv+silu output
    const float*  __restrict__ xdbl,  // (NR, 80): cols 48..79 = B|C
    bf16_t* __restrict__ xz,          // (NR, 3072): z at +DIN (read), yg at +0 (write)
    const float* __restrict__ A_log,  // (DIN, 16)
    const float* __restrict__ Dp)     // (DIN)
{
    __shared__ bf16_t dts[16][72];    // stride 72 breaks 4-way bank aliasing
    __shared__ bf16_t xcs[16][72];
    __shared__ float  BC[64][32];     // [l][0:16)=B, [16:32)=C
    __shared__ float  ybuf[16][68];

    int t = threadIdx.x;
    int s = t & 15, c = t >> 4;
    int blk = blockIdx.x;
    int b  = blk / (DIN/16);
    int d0 = (blk % (DIN/16)) * 16;
    float Aval = -__expf(A_log[(size_t)(d0+c)*DSTATE + s]);
    float Dv   = Dp[d0+c];
    float h = 0.f;
    size_t rbase = (size_t)b * Ln;

    for (int l0 = 0; l0 < Ln; l0 += 64) {
        #pragma unroll
        for (int pass = 0; pass < 4; pass++) {
            int i = t + pass*256;
            int sl = i >> 4, sc = i & 15;
            size_t row = rbase + l0 + sl;
            dts[sc][sl] = dtb[row*DIN + d0 + sc];
            xcs[sc][sl] = xcb[row*DIN + d0 + sc];
        }
        #pragma unroll
        for (int pass = 0; pass < 8; pass++) {
            int i = t + pass*256;
            int sl = i >> 5, f = i & 31;
            BC[sl][f] = xdbl[(rbase + l0 + sl)*XPN + DTRANK + f];
        }
        __syncthreads();

        #pragma unroll 8
        for (int l = 0; l < 64; l++) {
            float dtv = bf2f(dts[c][l]);
            float xv  = bf2f(xcs[c][l]);
            float Bv  = BC[l][s];
            float Cv  = BC[l][16+s];
            h = __expf(dtv*Aval)*h + dtv*xv*Bv;
            float p = h*Cv;
            p += __shfl_xor(p, 1);
            p += __shfl_xor(p, 2);
            p += __shfl_xor(p, 4);
            p += __shfl_xor(p, 8);
            if (s == 0) ybuf[c][l] = p + xv*Dv;
        }
        __syncthreads();

        #pragma unroll
        for (int pass = 0; pass < 4; pass++) {
            int i = t + pass*256;
            int sl = i >> 4, sc = i & 15;
            size_t row = rbase + l0 + sl;
            float zv = bf2f(xz[row*(2*DIN) + DIN + d0 + sc]);
            float y  = ybuf[sc][sl];
            xz[row*(2*DIN) + d0 + sc] = f2bf(y * zv * sigf(zv));
        }
        __syncthreads();
    }
}

extern "C" void kernel_launch(void* const* d_in, const int* in_sizes, int n_in,
                              void* d_out, int out_size, void* d_ws, size_t ws_size,
                              hipStream_t stream) {
    const float* x      = (const float*)d_in[0];
    const int*   mask   = (const int*)  d_in[1];
    const float* ln_g   = (const float*)d_in[2];
    const float* ln_b   = (const float*)d_in[3];
    const float* W_in   = (const float*)d_in[4];
    const float* conv_w = (const float*)d_in[5];
    const float* conv_b = (const float*)d_in[6];
    const float* W_xp   = (const float*)d_in[7];
    const float* W_dt   = (const float*)d_in[8];
    const float* b_dt   = (const float*)d_in[9];
    const float* A_log  = (const float*)d_in[10];
    const float* Dp     = (const float*)d_in[11];
    const float* W_out  = (const float*)d_in[12];
    float* out = (float*)d_out;

    // Workspace layout (~188 MB):
    char* wsb = (char*)d_ws;
    size_t off = 0;
    bf16_t* xz    = (bf16_t*)(wsb + off); off += (size_t)NR*3072*2;   // 100.7 MB
    bf16_t* xc    = (bf16_t*)(wsb + off); off += (size_t)NR*DIN*2;    //  50.3 MB
    float*  xdbl  = (float*) (wsb + off); off += (size_t)NR*XPN*4;    //   5.2 MB
    bf16_t* xnb   = (bf16_t*)(wsb + off); off += (size_t)NR*DIMn*2;   //  25.2 MB
    bf16_t* Winb  = (bf16_t*)(wsb + off); off += (size_t)(2*DIN)*DIMn*2; // 4.7 MB
    bf16_t* Woutb = (bf16_t*)(wsb + off); off += (size_t)DIMn*DIN*2;  //   2.4 MB
    // dt buffer lives in d_out (dead until final GEMM overwrites it):
    bf16_t* dtb = (bf16_t*)d_out;   // NR*DIN bf16 == out_size f32 bytes exactly

    // 0. weight conversion f32 -> bf16
    f2bf_kernel<<<(2*DIN*DIMn + 255)/256, 256, 0, stream>>>(W_in,  Winb,  2*DIN*DIMn);
    f2bf_kernel<<<(DIMn*DIN  + 255)/256, 256, 0, stream>>>(W_out, Woutb, DIMn*DIN);

    // 1. LayerNorm + mask -> xnb (bf16)
    ln_kernel<<<NR, 256, 0, stream>>>(x, mask, ln_g, ln_b, xnb);

    // 2. in_proj (MFMA): xz = xnb @ Winb^T  (M=16384, N=3072, K=768)
    mfma_gemm<0, bf16_t><<<dim3(3072/128, NR/128), 256, 0, stream>>>(
        xnb, DIMn, Winb, xz, 2*DIN, DIMn, nullptr, nullptr);

    // 3. depthwise conv + SiLU -> xc
    conv_silu_kernel<<<(NR*DIN)/256, 256, 0, stream>>>(xz, conv_w, conv_b, xc);

    // 4. x_proj: xdbl = xc @ W_xp^T  (N=80, K=1536)
    gemm_kernel<bf16_t, float, 0><<<dim3((XPN+63)/64, NR/64), 256, 0, stream>>>(
        xc, DIN, W_xp, xdbl, XPN, XPN, DIN, nullptr);

    // 5. dt = softplus(xdbl[:, :48] @ W_dt^T + b_dt) -> dtb (in d_out)
    gemm_kernel<float, bf16_t, 1><<<dim3(DIN/64, NR/64), 256, 0, stream>>>(
        xdbl, XPN, W_dt, dtb, DIN, DIN, DTRANK, b_dt);

    // 6. selective scan + D-skip + SiLU gate -> yg (x_in half of xz)
    scan_kernel<<<Bn*(DIN/16), 256, 0, stream>>>(dtb, xc, xdbl, xz, A_log, Dp);

    // 7. out_proj (MFMA) + residual: out = mf*(x + yg @ Woutb^T)  (N=768, K=1536)
    mfma_gemm<2, float><<<dim3(DIMn/128, NR/128), 256, 0, stream>>>(
        xz, 2*DIN, Woutb, out, DIMn, DIN, x, mask);
}

// Round 5
// 1060.484 us; speedup vs baseline: 3.4248x; 1.2671x over previous
//
#include <hip/hip_runtime.h>
#include <math.h>

#define Bn 8
#define Ln 2048
#define DIMn 768
#define DIN 1536           // D_INNER
#define DSTATE 16
#define DTRANK 48
#define XPN 80             // DT_RANK + 2*D_STATE
#define NR (Bn*Ln)         // 16384 rows
#define TL 64              // scan timestep tile

typedef unsigned short bf16_t;
typedef __attribute__((ext_vector_type(8))) short short8;   // 8 bf16 (4 VGPR)
typedef __attribute__((ext_vector_type(4))) float f32x4;

__device__ __forceinline__ float sigf(float v){ return 1.0f/(1.0f+__expf(-v)); }
__device__ __forceinline__ float bf2f(unsigned short u){
    return __uint_as_float(((unsigned int)u) << 16);
}
__device__ __forceinline__ unsigned short f2bf(float f){
    unsigned int x = __float_as_uint(f);
    unsigned int r = (x + 0x7FFFu + ((x >> 16) & 1u)) >> 16;
    return (unsigned short)r;
}

// quad-lane DPP permute-add building block (VALU pipe, no LDS)
template<int CTRL>
__device__ __forceinline__ float dpp_qperm(float x) {
    int v = __builtin_amdgcn_update_dpp(0, __float_as_int(x), CTRL, 0xF, 0xF, true);
    return __int_as_float(v);
}

// ---------------- f32 -> bf16 conversion ----------------
__global__ __launch_bounds__(256) void f2bf_kernel(
    const float* __restrict__ in, bf16_t* __restrict__ out, int n)
{
    int i = blockIdx.x*256 + threadIdx.x;
    if (i < n) out[i] = f2bf(in[i]);
}

// ---------------- LayerNorm + mask -> bf16 ----------------
__global__ __launch_bounds__(256) void ln_kernel(
    const float* __restrict__ x, const int* __restrict__ mask,
    const float* __restrict__ g, const float* __restrict__ bta,
    bf16_t* __restrict__ xn)
{
    int row = blockIdx.x;
    int t = threadIdx.x;
    const float* xr = x + (size_t)row * DIMn;
    float v0 = xr[t], v1 = xr[t+256], v2 = xr[t+512];
    float s  = v0+v1+v2;
    float sq = v0*v0+v1*v1+v2*v2;
    #pragma unroll
    for (int off = 32; off; off >>= 1) {
        s  += __shfl_down(s,  off, 64);
        sq += __shfl_down(sq, off, 64);
    }
    __shared__ float ls[4], lq[4];
    int wave = t >> 6, lane = t & 63;
    if (lane == 0) { ls[wave] = s; lq[wave] = sq; }
    __syncthreads();
    s  = ls[0]+ls[1]+ls[2]+ls[3];
    sq = lq[0]+lq[1]+lq[2]+lq[3];
    float mu  = s * (1.0f/DIMn);
    float var = sq * (1.0f/DIMn) - mu*mu;
    float rstd = rsqrtf(var + 1e-5f);
    float mf = (float)mask[row];
    bf16_t* o = xn + (size_t)row * DIMn;
    o[t]     = f2bf(((v0-mu)*rstd*g[t]     + bta[t])     * mf);
    o[t+256] = f2bf(((v1-mu)*rstd*g[t+256] + bta[t+256]) * mf);
    o[t+512] = f2bf(((v2-mu)*rstd*g[t+512] + bta[t+512]) * mf);
}

// ---------------- bf16 MFMA GEMM: C[M,N] = A[M,K] @ W[N,K]^T ----------------
// 128x128 block tile, 4 waves (2x2), wave = 64x64 via 4x4 mfma 16x16x32 tiles.
// Nb = valid N bound (W rows >= Nb zero-filled, stores guarded).
// EPI: 0 = store TC, 2 = f32 mf*(resid + acc)
template<int EPI, typename TC>
__global__ __launch_bounds__(256) void mfma_gemm(
    const bf16_t* __restrict__ A, int lda,
    const bf16_t* __restrict__ W,
    TC* __restrict__ C, int ldc, int K, int Nb,
    const float* __restrict__ resid, const int* __restrict__ mask)
{
    int wave = threadIdx.x >> 6, lane = threadIdx.x & 63;
    int m0 = blockIdx.y*128 + (wave>>1)*64;
    int n0 = blockIdx.x*128 + (wave&1)*64;
    int lr = lane & 15;
    int ko = (lane>>4)*8;
    const bf16_t* Ap = A + (size_t)(m0+lr)*lda + ko;
    const bf16_t* Wp = W + (size_t)(n0+lr)*K   + ko;
    f32x4 acc[4][4] = {};

    for (int k0 = 0; k0 < K; k0 += 32) {
        short8 a[4], b[4];
        #pragma unroll
        for (int i = 0; i < 4; i++)
            a[i] = *(const short8*)(Ap + (size_t)i*16*lda + k0);
        #pragma unroll
        for (int i = 0; i < 4; i++) {
            if (n0 + i*16 < Nb)
                b[i] = *(const short8*)(Wp + (size_t)i*16*K + k0);
            else
                b[i] = short8{0,0,0,0,0,0,0,0};
        }
        #pragma unroll
        for (int mt = 0; mt < 4; mt++)
            #pragma unroll
            for (int nt = 0; nt < 4; nt++)
                acc[mt][nt] = __builtin_amdgcn_mfma_f32_16x16x32_bf16(
                    a[mt], b[nt], acc[mt][nt], 0, 0, 0);
    }

    int rb = (lane>>4)*4;
    #pragma unroll
    for (int mt = 0; mt < 4; mt++) {
        #pragma unroll
        for (int nt = 0; nt < 4; nt++) {
            int col = n0 + nt*16 + lr;
            if (col >= Nb) continue;
            #pragma unroll
            for (int r = 0; r < 4; r++) {
                int row = m0 + mt*16 + rb + r;
                float v = acc[mt][nt][r];
                if (EPI == 2)
                    v = (float)mask[row] * (resid[(size_t)row*ldc + col] + v);
                if constexpr (sizeof(TC) == 2)
                    C[(size_t)row*ldc + col] = f2bf(v);
                else
                    C[(size_t)row*ldc + col] = v;
            }
        }
    }
}

// ---- typed helpers for the small f32 GEMM ----
__device__ __forceinline__ void ldA4(const float* p, float v[4]) {
    float4 t = *(const float4*)p; v[0]=t.x; v[1]=t.y; v[2]=t.z; v[3]=t.w;
}
__device__ __forceinline__ void ldA4(const bf16_t* p, float v[4]) {
    ushort4 t = *(const ushort4*)p;
    v[0]=bf2f(t.x); v[1]=bf2f(t.y); v[2]=bf2f(t.z); v[3]=bf2f(t.w);
}
__device__ __forceinline__ void stC4(float* p, const float v[4]) {
    *(float4*)p = make_float4(v[0],v[1],v[2],v[3]);
}
__device__ __forceinline__ void stC4(bf16_t* p, const float v[4]) {
    ushort4 t; t.x=f2bf(v[0]); t.y=f2bf(v[1]); t.z=f2bf(v[2]); t.w=f2bf(v[3]);
    *(ushort4*)p = t;
}

// ---------------- small GEMM (dt_proj): C = softplus(A @ W^T + bias) ----------------
template<typename TA, typename TC, int EPI>
__global__ __launch_bounds__(256) void gemm_kernel(
    const TA* __restrict__ A, int lda,
    const float* __restrict__ W,
    TC* __restrict__ C, int ldc,
    int N, int K,
    const float* __restrict__ bias)
{
    __shared__ float As[16][64];
    __shared__ float Ws[16][64];
    int m0 = blockIdx.y * 64;
    int n0 = blockIdx.x * 64;
    int t  = threadIdx.x;
    int lr = t >> 2;
    int lc = (t & 3) * 4;
    int tx = t & 15, ty = t >> 4;
    float acc[4][4] = {};

    for (int k0 = 0; k0 < K; k0 += 16) {
        float av[4];
        ldA4(A + (size_t)(m0+lr)*lda + k0 + lc, av);
        float wv[4] = {0.f,0.f,0.f,0.f};
        if (n0 + lr < N) {
            float4 w4 = *(const float4*)(W + (size_t)(n0+lr)*K + k0 + lc);
            wv[0]=w4.x; wv[1]=w4.y; wv[2]=w4.z; wv[3]=w4.w;
        }
        __syncthreads();
        As[lc+0][lr]=av[0]; As[lc+1][lr]=av[1]; As[lc+2][lr]=av[2]; As[lc+3][lr]=av[3];
        Ws[lc+0][lr]=wv[0]; Ws[lc+1][lr]=wv[1]; Ws[lc+2][lr]=wv[2]; Ws[lc+3][lr]=wv[3];
        __syncthreads();
        #pragma unroll
        for (int kk = 0; kk < 16; kk++) {
            const float4 a4 = *(const float4*)&As[kk][ty*4];
            const float4 w4 = *(const float4*)&Ws[kk][tx*4];
            float a[4] = {a4.x,a4.y,a4.z,a4.w};
            float w[4] = {w4.x,w4.y,w4.z,w4.w};
            #pragma unroll
            for (int i = 0; i < 4; i++)
                #pragma unroll
                for (int j = 0; j < 4; j++)
                    acc[i][j] = fmaf(a[i], w[j], acc[i][j]);
        }
    }

    int ncol = n0 + tx*4;
    if (ncol >= N) return;
    #pragma unroll
    for (int i = 0; i < 4; i++) {
        int row = m0 + ty*4 + i;
        TC* cp = C + (size_t)row*ldc + ncol;
        float v[4];
        #pragma unroll
        for (int j = 0; j < 4; j++) {
            float u = acc[i][j] + bias[ncol+j];
            v[j] = (u > 20.f) ? u : log1pf(__expf(u));
        }
        stC4(cp, v);
    }
}

// ---------------- depthwise causal conv (width 4) + SiLU, 2 ch/thread ----------------
__global__ __launch_bounds__(256) void conv_silu_kernel(
    const bf16_t* __restrict__ xz,
    const float* __restrict__ cw,
    const float* __restrict__ cb,
    bf16_t* __restrict__ xc)
{
    int idx = blockIdx.x*256 + threadIdx.x;       // over NR*DIN/2
    int dh = idx % (DIN/2);
    int r  = idx / (DIN/2);
    int l  = r % Ln;
    int d  = dh*2;
    float4 w0 = *(const float4*)(cw + d*4);
    float4 w1 = *(const float4*)(cw + d*4 + 4);
    float a0 = cb[d], a1 = cb[d+1];
    #pragma unroll
    for (int j = 0; j < 4; j++) {
        int ll = l - 3 + j;
        if (ll >= 0) {
            ushort2 v = *(const ushort2*)(xz + (size_t)(r-3+j)*(2*DIN) + d);
            a0 += bf2f(v.x) * ((const float*)&w0)[j];
            a1 += bf2f(v.y) * ((const float*)&w1)[j];
        }
    }
    ushort2 o; o.x = f2bf(a0*sigf(a0)); o.y = f2bf(a1*sigf(a1));
    *(ushort2*)(xc + (size_t)r*DIN + d) = o;
}

// ---------------- selective scan: 4 states/thread, DPP quad reduce ----------------
// 64-thread blocks (1 wave): 16 channels; lane = (c = t>>2, g = t&3), states 4g..4g+3.
// yg written into the dead x_in half of xz.
__global__ __launch_bounds__(64) void scan_kernel(
    const bf16_t* __restrict__ dtb,   // (NR, DIN)
    const bf16_t* __restrict__ xcb,   // (NR, DIN)
    const bf16_t* __restrict__ xdbl,  // (NR, 80): cols 48..79 = B|C (bf16)
    bf16_t* __restrict__ xz,          // z read at +DIN, yg write at +0
    const float* __restrict__ A_log,  // (DIN, 16)
    const float* __restrict__ Dp)
{
    __shared__ float dts[TL][17];
    __shared__ float xcs[TL][17];
    __shared__ float Bs [TL][17];
    __shared__ float Cs [TL][17];
    __shared__ float ybuf[TL][17];

    int t = threadIdx.x;
    int c = t >> 2;
    int g = t & 3;
    int blk = blockIdx.x;
    int b  = blk / (DIN/16);
    int d0 = (blk % (DIN/16)) * 16;
    int d  = d0 + c;

    float A2[4], h[4] = {0.f,0.f,0.f,0.f};
    #pragma unroll
    for (int j = 0; j < 4; j++)
        A2[j] = -__expf(A_log[(size_t)d*DSTATE + 4*g + j]) * 1.44269504f;
    float Dv = Dp[d];
    size_t rbase = (size_t)b * Ln;

    for (int l0 = 0; l0 < Ln; l0 += TL) {
        // ---- stage tile: thread t handles timestep row l0+t ----
        {
            size_t row = rbase + l0 + t;
            const ushort4* dp = (const ushort4*)(dtb + row*DIN + d0);
            const ushort4* xp = (const ushort4*)(xcb + row*DIN + d0);
            #pragma unroll
            for (int q = 0; q < 4; q++) {
                ushort4 dv = dp[q], xv = xp[q];
                dts[t][q*4+0]=bf2f(dv.x); dts[t][q*4+1]=bf2f(dv.y);
                dts[t][q*4+2]=bf2f(dv.z); dts[t][q*4+3]=bf2f(dv.w);
                xcs[t][q*4+0]=bf2f(xv.x); xcs[t][q*4+1]=bf2f(xv.y);
                xcs[t][q*4+2]=bf2f(xv.z); xcs[t][q*4+3]=bf2f(xv.w);
            }
            const ushort4* bp = (const ushort4*)(xdbl + row*XPN + DTRANK);
            #pragma unroll
            for (int q = 0; q < 4; q++) {
                ushort4 bv = bp[q];
                Bs[t][q*4+0]=bf2f(bv.x); Bs[t][q*4+1]=bf2f(bv.y);
                Bs[t][q*4+2]=bf2f(bv.z); Bs[t][q*4+3]=bf2f(bv.w);
                ushort4 cv = bp[4+q];
                Cs[t][q*4+0]=bf2f(cv.x); Cs[t][q*4+1]=bf2f(cv.y);
                Cs[t][q*4+2]=bf2f(cv.z); Cs[t][q*4+3]=bf2f(cv.w);
            }
        }
        __syncthreads();

        // ---- serial recurrence over the tile ----
        #pragma unroll 8
        for (int l = 0; l < TL; l++) {
            float dtv = dts[l][c];
            float xv  = xcs[l][c];
            float u   = dtv * xv;
            float p   = 0.f;
            #pragma unroll
            for (int j = 0; j < 4; j++) {
                float e = __builtin_amdgcn_exp2f(dtv * A2[j]);
                h[j] = e*h[j] + u*Bs[l][4*g+j];
                p = fmaf(h[j], Cs[l][4*g+j], p);
            }
            p += dpp_qperm<0xB1>(p);   // quad xor 1
            p += dpp_qperm<0x4E>(p);   // quad xor 2
            if (g == 0) ybuf[l][c] = p + xv*Dv;
        }
        __syncthreads();

        // ---- gate with z, write yg ----
        {
            size_t row = rbase + l0 + t;
            const ushort4* zp = (const ushort4*)(xz + row*(2*DIN) + DIN + d0);
            ushort4* op = (ushort4*)(xz + row*(2*DIN) + d0);
            #pragma unroll
            for (int q = 0; q < 4; q++) {
                ushort4 zv = zp[q];
                float z0 = bf2f(zv.x), z1 = bf2f(zv.y), z2 = bf2f(zv.z), z3 = bf2f(zv.w);
                ushort4 o;
                o.x = f2bf(ybuf[t][q*4+0] * z0 * sigf(z0));
                o.y = f2bf(ybuf[t][q*4+1] * z1 * sigf(z1));
                o.z = f2bf(ybuf[t][q*4+2] * z2 * sigf(z2));
                o.w = f2bf(ybuf[t][q*4+3] * z3 * sigf(z3));
                op[q] = o;
            }
        }
        __syncthreads();
    }
}

extern "C" void kernel_launch(void* const* d_in, const int* in_sizes, int n_in,
                              void* d_out, int out_size, void* d_ws, size_t ws_size,
                              hipStream_t stream) {
    const float* x      = (const float*)d_in[0];
    const int*   mask   = (const int*)  d_in[1];
    const float* ln_g   = (const float*)d_in[2];
    const float* ln_b   = (const float*)d_in[3];
    const float* W_in   = (const float*)d_in[4];
    const float* conv_w = (const float*)d_in[5];
    const float* conv_b = (const float*)d_in[6];
    const float* W_xp   = (const float*)d_in[7];
    const float* W_dt   = (const float*)d_in[8];
    const float* b_dt   = (const float*)d_in[9];
    const float* A_log  = (const float*)d_in[10];
    const float* Dp     = (const float*)d_in[11];
    const float* W_out  = (const float*)d_in[12];
    float* out = (float*)d_out;

    // Workspace layout (~186 MB):
    char* wsb = (char*)d_ws;
    size_t off = 0;
    bf16_t* xz    = (bf16_t*)(wsb + off); off += (size_t)NR*3072*2;      // 100.7 MB
    bf16_t* xc    = (bf16_t*)(wsb + off); off += (size_t)NR*DIN*2;       //  50.3 MB
    bf16_t* xdbl  = (bf16_t*)(wsb + off); off += (size_t)NR*XPN*2;       //   2.6 MB
    bf16_t* xnb   = (bf16_t*)(wsb + off); off += (size_t)NR*DIMn*2;      //  25.2 MB
    bf16_t* Winb  = (bf16_t*)(wsb + off); off += (size_t)(2*DIN)*DIMn*2; //   4.7 MB
    bf16_t* Woutb = (bf16_t*)(wsb + off); off += (size_t)DIMn*DIN*2;     //   2.4 MB
    bf16_t* Wxpb  = (bf16_t*)(wsb + off); off += (size_t)XPN*DIN*2;      //   0.25 MB
    // dt buffer lives in d_out (dead until final GEMM overwrites it):
    bf16_t* dtb = (bf16_t*)d_out;   // NR*DIN bf16 == out_size f32 bytes exactly

    // 0. weight conversion f32 -> bf16
    f2bf_kernel<<<(2*DIN*DIMn + 255)/256, 256, 0, stream>>>(W_in,  Winb,  2*DIN*DIMn);
    f2bf_kernel<<<(DIMn*DIN  + 255)/256, 256, 0, stream>>>(W_out, Woutb, DIMn*DIN);
    f2bf_kernel<<<(XPN*DIN   + 255)/256, 256, 0, stream>>>(W_xp,  Wxpb,  XPN*DIN);

    // 1. LayerNorm + mask -> xnb (bf16)
    ln_kernel<<<NR, 256, 0, stream>>>(x, mask, ln_g, ln_b, xnb);

    // 2. in_proj (MFMA): xz = xnb @ Winb^T  (M=16384, N=3072, K=768)
    mfma_gemm<0, bf16_t><<<dim3(3072/128, NR/128), 256, 0, stream>>>(
        xnb, DIMn, Winb, xz, 2*DIN, DIMn, 3072, nullptr, nullptr);

    // 3. depthwise conv + SiLU -> xc
    conv_silu_kernel<<<(NR*DIN/2)/256, 256, 0, stream>>>(xz, conv_w, conv_b, xc);

    // 4. x_proj (MFMA): xdbl = xc @ Wxpb^T  (N=80 -> 1 guarded 128-tile, K=1536)
    mfma_gemm<0, bf16_t><<<dim3(1, NR/128), 256, 0, stream>>>(
        xc, DIN, Wxpb, xdbl, XPN, DIN, XPN, nullptr, nullptr);

    // 5. dt = softplus(xdbl[:, :48] @ W_dt^T + b_dt) -> dtb (in d_out)
    gemm_kernel<bf16_t, bf16_t, 1><<<dim3(DIN/64, NR/64), 256, 0, stream>>>(
        xdbl, XPN, W_dt, dtb, DIN, DIN, DTRANK, b_dt);

    // 6. selective scan + D-skip + SiLU gate -> yg (x_in half of xz)
    scan_kernel<<<Bn*(DIN/16), 64, 0, stream>>>(dtb, xc, xdbl, xz, A_log, Dp);

    // 7. out_proj (MFMA) + residual: out = mf*(x + yg @ Woutb^T)  (N=768, K=1536)
    mfma_gemm<2, float><<<dim3(DIMn/128, NR/128), 256, 0, stream>>>(
        xz, 2*DIN, Woutb, out, DIMn, DIN, DIMn, x, mask);
}

// Round 6
// 814.205 us; speedup vs baseline: 4.4608x; 1.3025x over previous
//
#include <hip/hip_runtime.h>
#include <math.h>

#define Bn 8
#define Ln 2048
#define DIMn 768
#define DIN 1536           // D_INNER
#define DSTATE 16
#define DTRANK 48
#define XPN 80             // DT_RANK + 2*D_STATE
#define NR (Bn*Ln)         // 16384 rows
#define CH 128             // scan chunk length
#define NCH (Ln/CH)        // 16 chunks
#define NDG (DIN/16)       // 96 channel groups
#define TL 64              // scan staging tile

typedef unsigned short bf16_t;
typedef __attribute__((ext_vector_type(8))) short short8;   // 8 bf16 (4 VGPR)
typedef __attribute__((ext_vector_type(4))) float f32x4;

__device__ __forceinline__ float sigf(float v){ return 1.0f/(1.0f+__expf(-v)); }
__device__ __forceinline__ float bf2f(unsigned short u){
    return __uint_as_float(((unsigned int)u) << 16);
}
__device__ __forceinline__ unsigned short f2bf(float f){
    unsigned int x = __float_as_uint(f);
    unsigned int r = (x + 0x7FFFu + ((x >> 16) & 1u)) >> 16;
    return (unsigned short)r;
}

// async global->LDS, 16B per lane; LDS dest = uniform base + lane*16
__device__ __forceinline__ void async_ld16(const bf16_t* g, bf16_t* l) {
    __builtin_amdgcn_global_load_lds(
        (const __attribute__((address_space(1))) unsigned int*)g,
        (__attribute__((address_space(3))) unsigned int*)l,
        16, 0, 0);
}

// quad-lane DPP permute-add (VALU pipe)
template<int CTRL>
__device__ __forceinline__ float dpp_qperm(float x) {
    int v = __builtin_amdgcn_update_dpp(0, __float_as_int(x), CTRL, 0xF, 0xF, true);
    return __int_as_float(v);
}

// ---------------- weight prep ----------------
__global__ __launch_bounds__(256) void f2bf_kernel(
    const float* __restrict__ in, bf16_t* __restrict__ out, int n)
{
    int i = blockIdx.x*256 + threadIdx.x;
    if (i < n) out[i] = f2bf(in[i]);
}
// W_xp (80,1536) -> (128,1536) zero row-padded
__global__ __launch_bounds__(256) void padxp_kernel(
    const float* __restrict__ W, bf16_t* __restrict__ out)
{
    int i = blockIdx.x*256 + threadIdx.x;   // < 128*1536
    int row = i / DIN, col = i % DIN;
    out[i] = (row < XPN) ? f2bf(W[row*DIN + col]) : 0;
}
// W_dt (1536,48) -> (1536,64) zero col-padded
__global__ __launch_bounds__(256) void paddt_kernel(
    const float* __restrict__ W, bf16_t* __restrict__ out)
{
    int i = blockIdx.x*256 + threadIdx.x;   // < 1536*64
    int row = i >> 6, col = i & 63;
    out[i] = (col < DTRANK) ? f2bf(W[row*DTRANK + col]) : 0;
}

// ---------------- LayerNorm + mask -> bf16 ----------------
__global__ __launch_bounds__(256) void ln_kernel(
    const float* __restrict__ x, const int* __restrict__ mask,
    const float* __restrict__ g, const float* __restrict__ bta,
    bf16_t* __restrict__ xn)
{
    int row = blockIdx.x;
    int t = threadIdx.x;
    const float* xr = x + (size_t)row * DIMn;
    float v0 = xr[t], v1 = xr[t+256], v2 = xr[t+512];
    float s  = v0+v1+v2;
    float sq = v0*v0+v1*v1+v2*v2;
    #pragma unroll
    for (int off = 32; off; off >>= 1) {
        s  += __shfl_down(s,  off, 64);
        sq += __shfl_down(sq, off, 64);
    }
    __shared__ float ls[4], lq[4];
    int wave = t >> 6, lane = t & 63;
    if (lane == 0) { ls[wave] = s; lq[wave] = sq; }
    __syncthreads();
    s  = ls[0]+ls[1]+ls[2]+ls[3];
    sq = lq[0]+lq[1]+lq[2]+lq[3];
    float mu  = s * (1.0f/DIMn);
    float var = sq * (1.0f/DIMn) - mu*mu;
    float rstd = rsqrtf(var + 1e-5f);
    float mf = (float)mask[row];
    bf16_t* o = xn + (size_t)row * DIMn;
    o[t]     = f2bf(((v0-mu)*rstd*g[t]     + bta[t])     * mf);
    o[t+256] = f2bf(((v1-mu)*rstd*g[t+256] + bta[t+256]) * mf);
    o[t+512] = f2bf(((v2-mu)*rstd*g[t+512] + bta[t+512]) * mf);
}

// ---------------- LDS-staged bf16 MFMA GEMM: C[M,N] = A[M,K] @ W[N,K]^T ------
// 128x128 tile, BK=32, 4 waves (2x2). LDS holds tiles in MFMA-fragment order:
// subtile st (16 rows x 32 k) = 64 lanes x 16B, lane l = row(l&15), k (l>>4)*8.
// global_load_lds lands lane l's 16B at base+l*16 => ds_read_b128 conflict-free.
// EPI: 0 = store bf16, 1 = softplus(acc+bias[n]) bf16, 2 = f32 mf*(resid+acc)
template<int EPI, typename TC>
__global__ __launch_bounds__(256) void mfma_gemm(
    const bf16_t* __restrict__ A, int lda,
    const bf16_t* __restrict__ W, int ldw,
    TC* __restrict__ C, int ldc, int K, int Nb,
    const float* __restrict__ bias,
    const float* __restrict__ resid, const int* __restrict__ mask)
{
    __shared__ __align__(16) bf16_t Als[8*512];
    __shared__ __align__(16) bf16_t Bls[8*512];
    int tid  = threadIdx.x;
    int wave = tid >> 6, lane = tid & 63;
    int mblk = blockIdx.y*128, nblk = blockIdx.x*128;
    int lr16 = lane & 15, kq = lane >> 4;
    int wr = wave >> 1, wc = wave & 1;
    f32x4 acc[4][4] = {};

    for (int k0 = 0; k0 < K; k0 += 32) {
        #pragma unroll
        for (int q = 0; q < 4; q++) {
            int id = wave*4 + q;
            if (id < 8) {
                const bf16_t* g = A + (size_t)(mblk + id*16 + lr16)*lda + k0 + kq*8;
                async_ld16(g, Als + id*512);
            } else {
                const bf16_t* g = W + (size_t)(nblk + (id-8)*16 + lr16)*ldw + k0 + kq*8;
                async_ld16(g, Bls + (id-8)*512);
            }
        }
        __syncthreads();
        short8 a[4], b[4];
        #pragma unroll
        for (int i = 0; i < 4; i++)
            a[i] = *(const short8*)(Als + (wr*4+i)*512 + lane*8);
        #pragma unroll
        for (int i = 0; i < 4; i++)
            b[i] = *(const short8*)(Bls + (wc*4+i)*512 + lane*8);
        #pragma unroll
        for (int mt = 0; mt < 4; mt++)
            #pragma unroll
            for (int nt = 0; nt < 4; nt++)
                acc[mt][nt] = __builtin_amdgcn_mfma_f32_16x16x32_bf16(
                    a[mt], b[nt], acc[mt][nt], 0, 0, 0);
        __syncthreads();
    }

    int m0 = mblk + wr*64, n0 = nblk + wc*64;
    int rb = kq*4;
    #pragma unroll
    for (int mt = 0; mt < 4; mt++) {
        #pragma unroll
        for (int nt = 0; nt < 4; nt++) {
            int col = n0 + nt*16 + lr16;
            if (col >= Nb) continue;
            #pragma unroll
            for (int r = 0; r < 4; r++) {
                int row = m0 + mt*16 + rb + r;
                float v = acc[mt][nt][r];
                if (EPI == 1) {
                    float u = v + bias[col];
                    v = (u > 20.f) ? u : log1pf(__expf(u));
                } else if (EPI == 2) {
                    v = (float)mask[row] * (resid[(size_t)row*ldc + col] + v);
                }
                if constexpr (sizeof(TC) == 2)
                    C[(size_t)row*ldc + col] = f2bf(v);
                else
                    C[(size_t)row*ldc + col] = v;
            }
        }
    }
}

// ---------------- depthwise causal conv (width 4) + SiLU, 2 ch/thread --------
__global__ __launch_bounds__(256) void conv_silu_kernel(
    const bf16_t* __restrict__ xz,
    const float* __restrict__ cw,
    const float* __restrict__ cb,
    bf16_t* __restrict__ xc)
{
    int idx = blockIdx.x*256 + threadIdx.x;       // over NR*DIN/2
    int dh = idx % (DIN/2);
    int r  = idx / (DIN/2);
    int l  = r % Ln;
    int d  = dh*2;
    float4 w0 = *(const float4*)(cw + d*4);
    float4 w1 = *(const float4*)(cw + d*4 + 4);
    float a0 = cb[d], a1 = cb[d+1];
    #pragma unroll
    for (int j = 0; j < 4; j++) {
        int ll = l - 3 + j;
        if (ll >= 0) {
            ushort2 v = *(const ushort2*)(xz + (size_t)(r-3+j)*(2*DIN) + d);
            a0 += bf2f(v.x) * ((const float*)&w0)[j];
            a1 += bf2f(v.y) * ((const float*)&w1)[j];
        }
    }
    ushort2 o; o.x = f2bf(a0*sigf(a0)); o.y = f2bf(a1*sigf(a1));
    *(ushort2*)(xc + (size_t)r*DIN + d) = o;
}

// ---------------- scan pass 1: per-chunk local end-state ---------------------
// block = (b, 16-ch group, chunk). 64 thr: c=t>>2 (channel), g=t&3 (4 states).
// Emits hend (h at chunk end from h0=0) and sum(dt) over chunk per channel.
__global__ __launch_bounds__(64) void scan1_kernel(
    const bf16_t* __restrict__ dtb,   // (NR, DIN)
    const bf16_t* __restrict__ xcb,   // (NR, DIN)
    const bf16_t* __restrict__ xdbl,  // (NR, 80): cols 48..63 = B
    const float* __restrict__ A_log,
    float* __restrict__ hend,         // (12288*64) float4
    float* __restrict__ sumdt)        // (12288*16)
{
    __shared__ bf16_t dts[TL][20];
    __shared__ bf16_t xcs[TL][20];
    __shared__ float  Bs [TL][16];

    int t = threadIdx.x;
    int c = t >> 2, g = t & 3;
    int blk = blockIdx.x;
    int ch  = blk & (NCH-1);
    int bdg = blk >> 4;
    int b   = bdg / NDG, dg = bdg % NDG;
    int d0  = dg*16, d = d0 + c;

    float A2[4], h[4] = {0.f,0.f,0.f,0.f};
    #pragma unroll
    for (int j = 0; j < 4; j++)
        A2[j] = -__expf(A_log[(size_t)d*DSTATE + 4*g + j]) * 1.44269504f;
    float sdt = 0.f;
    size_t rbase = (size_t)b*Ln + (size_t)ch*CH;

    for (int l0 = 0; l0 < CH; l0 += TL) {
        size_t row = rbase + l0 + t;
        const ushort4* dp = (const ushort4*)(dtb + row*DIN + d0);
        const ushort4* xp = (const ushort4*)(xcb + row*DIN + d0);
        #pragma unroll
        for (int q = 0; q < 4; q++) {
            *(ushort4*)&dts[t][q*4] = dp[q];
            *(ushort4*)&xcs[t][q*4] = xp[q];
        }
        const ushort4* bp = (const ushort4*)(xdbl + row*XPN + DTRANK);
        #pragma unroll
        for (int q = 0; q < 4; q++) {
            ushort4 bv = bp[q];
            Bs[t][q*4+0]=bf2f(bv.x); Bs[t][q*4+1]=bf2f(bv.y);
            Bs[t][q*4+2]=bf2f(bv.z); Bs[t][q*4+3]=bf2f(bv.w);
        }
        __syncthreads();
        #pragma unroll 8
        for (int l = 0; l < TL; l++) {
            float dtv = bf2f(dts[l][c]);
            float xv  = bf2f(xcs[l][c]);
            sdt += dtv;
            float u = dtv * xv;
            #pragma unroll
            for (int j = 0; j < 4; j++) {
                float e = __builtin_amdgcn_exp2f(dtv * A2[j]);
                h[j] = e*h[j] + u*Bs[l][4*g+j];
            }
        }
        __syncthreads();
    }
    float4 hv = make_float4(h[0], h[1], h[2], h[3]);
    *(float4*)&hend[(size_t)(blk*64 + t)*4] = hv;
    if (g == 0) sumdt[blk*16 + c] = sdt;
}

// ---------------- scan pass 2: prefix-fixup + local scan + y + gate ----------
__global__ __launch_bounds__(64) void scan2_kernel(
    const bf16_t* __restrict__ dtb,
    const bf16_t* __restrict__ xcb,
    const bf16_t* __restrict__ xdbl,  // cols 48..63=B, 64..79=C
    bf16_t* __restrict__ xz,          // z read at +DIN, yg write at +0
    const float* __restrict__ A_log,
    const float* __restrict__ Dp,
    const float* __restrict__ hend,
    const float* __restrict__ sumdt)
{
    __shared__ bf16_t dts[TL][20];
    __shared__ bf16_t xcs[TL][20];
    __shared__ float  Bs [TL][16];
    __shared__ float  Cs [TL][16];
    __shared__ float  ybuf[TL][17];

    int t = threadIdx.x;
    int c = t >> 2, g = t & 3;
    int blk = blockIdx.x;
    int ch  = blk & (NCH-1);
    int bdg = blk >> 4;
    int b   = bdg / NDG, dg = bdg % NDG;
    int d0  = dg*16, d = d0 + c;

    float A2[4], h[4] = {0.f,0.f,0.f,0.f};
    #pragma unroll
    for (int j = 0; j < 4; j++)
        A2[j] = -__expf(A_log[(size_t)d*DSTATE + 4*g + j]) * 1.44269504f;
    float Dv = Dp[d];

    // chunk-prefix: compose earlier chunks' (Acum, hend)
    for (int cc = 0; cc < ch; cc++) {
        int wblk = (bdg << 4) | cc;
        float sd = sumdt[wblk*16 + c];
        float4 he = *(const float4*)&hend[(size_t)(wblk*64 + t)*4];
        #pragma unroll
        for (int j = 0; j < 4; j++) {
            float e = __builtin_amdgcn_exp2f(A2[j]*sd);
            h[j] = e*h[j] + ((const float*)&he)[j];
        }
    }

    size_t rbase = (size_t)b*Ln + (size_t)ch*CH;
    for (int l0 = 0; l0 < CH; l0 += TL) {
        size_t row = rbase + l0 + t;
        const ushort4* dp = (const ushort4*)(dtb + row*DIN + d0);
        const ushort4* xp = (const ushort4*)(xcb + row*DIN + d0);
        #pragma unroll
        for (int q = 0; q < 4; q++) {
            *(ushort4*)&dts[t][q*4] = dp[q];
            *(ushort4*)&xcs[t][q*4] = xp[q];
        }
        const ushort4* bp = (const ushort4*)(xdbl + row*XPN + DTRANK);
        #pragma unroll
        for (int q = 0; q < 4; q++) {
            ushort4 bv = bp[q];
            Bs[t][q*4+0]=bf2f(bv.x); Bs[t][q*4+1]=bf2f(bv.y);
            Bs[t][q*4+2]=bf2f(bv.z); Bs[t][q*4+3]=bf2f(bv.w);
            ushort4 cv = bp[4+q];
            Cs[t][q*4+0]=bf2f(cv.x); Cs[t][q*4+1]=bf2f(cv.y);
            Cs[t][q*4+2]=bf2f(cv.z); Cs[t][q*4+3]=bf2f(cv.w);
        }
        __syncthreads();
        #pragma unroll 8
        for (int l = 0; l < TL; l++) {
            float dtv = bf2f(dts[l][c]);
            float xv  = bf2f(xcs[l][c]);
            float u   = dtv * xv;
            float p   = 0.f;
            #pragma unroll
            for (int j = 0; j < 4; j++) {
                float e = __builtin_amdgcn_exp2f(dtv * A2[j]);
                h[j] = e*h[j] + u*Bs[l][4*g+j];
                p = fmaf(h[j], Cs[l][4*g+j], p);
            }
            p += dpp_qperm<0xB1>(p);
            p += dpp_qperm<0x4E>(p);
            if (g == 0) ybuf[l][c] = p + xv*Dv;
        }
        __syncthreads();
        // gate with z, write yg (coalesced, thread t = row l0+t)
        {
            const ushort4* zp = (const ushort4*)(xz + row*(2*DIN) + DIN + d0);
            ushort4* op = (ushort4*)(xz + row*(2*DIN) + d0);
            #pragma unroll
            for (int q = 0; q < 4; q++) {
                ushort4 zv = zp[q];
                float z0 = bf2f(zv.x), z1 = bf2f(zv.y), z2 = bf2f(zv.z), z3 = bf2f(zv.w);
                ushort4 o;
                o.x = f2bf(ybuf[t][q*4+0] * z0 * sigf(z0));
                o.y = f2bf(ybuf[t][q*4+1] * z1 * sigf(z1));
                o.z = f2bf(ybuf[t][q*4+2] * z2 * sigf(z2));
                o.w = f2bf(ybuf[t][q*4+3] * z3 * sigf(z3));
                op[q] = o;
            }
        }
        __syncthreads();
    }
}

extern "C" void kernel_launch(void* const* d_in, const int* in_sizes, int n_in,
                              void* d_out, int out_size, void* d_ws, size_t ws_size,
                              hipStream_t stream) {
    const float* x      = (const float*)d_in[0];
    const int*   mask   = (const int*)  d_in[1];
    const float* ln_g   = (const float*)d_in[2];
    const float* ln_b   = (const float*)d_in[3];
    const float* W_in   = (const float*)d_in[4];
    const float* conv_w = (const float*)d_in[5];
    const float* conv_b = (const float*)d_in[6];
    const float* W_xp   = (const float*)d_in[7];
    const float* W_dt   = (const float*)d_in[8];
    const float* b_dt   = (const float*)d_in[9];
    const float* A_log  = (const float*)d_in[10];
    const float* Dp     = (const float*)d_in[11];
    const float* W_out  = (const float*)d_in[12];
    float* out = (float*)d_out;

    // Workspace (~186 MB). xnb region is reused after in_proj for the padded
    // small weights and the scan chunk-state (disjoint subregions, live ranges ok).
    char* wsb = (char*)d_ws;
    size_t off = 0;
    bf16_t* xz    = (bf16_t*)(wsb + off); off += (size_t)NR*3072*2;      // 100.7 MB
    bf16_t* xc    = (bf16_t*)(wsb + off); off += (size_t)NR*DIN*2;       //  50.3 MB
    bf16_t* xdbl  = (bf16_t*)(wsb + off); off += (size_t)NR*XPN*2;       //   2.6 MB
    char*   xnbR  = (wsb + off);          off += (size_t)NR*DIMn*2;      //  25.2 MB
    bf16_t* Winb  = (bf16_t*)(wsb + off); off += (size_t)(2*DIN)*DIMn*2; //   4.7 MB
    bf16_t* Woutb = (bf16_t*)(wsb + off); off += (size_t)DIMn*DIN*2;     //   2.4 MB

    bf16_t* xnb   = (bf16_t*)xnbR;
    // aliases inside xnb region (live after in_proj):
    float*  hend  = (float*)xnbR;                          // 12288*64*4 f = 12.6 MB
    float*  sumdt = hend + (size_t)12288*64*4;             // 12288*16 f  =  0.8 MB
    bf16_t* Wxpb  = (bf16_t*)(sumdt + (size_t)12288*16);   // 128*1536    =  0.4 MB
    bf16_t* Wdtb  = Wxpb + (size_t)128*DIN;                // 1536*64     =  0.2 MB

    // dt buffer lives in d_out (dead until final GEMM overwrites it)
    bf16_t* dtb = (bf16_t*)d_out;

    // 0. big-weight conversion
    f2bf_kernel<<<(2*DIN*DIMn + 255)/256, 256, 0, stream>>>(W_in,  Winb,  2*DIN*DIMn);
    f2bf_kernel<<<(DIMn*DIN  + 255)/256, 256, 0, stream>>>(W_out, Woutb, DIMn*DIN);

    // 1. LayerNorm + mask -> xnb
    ln_kernel<<<NR, 256, 0, stream>>>(x, mask, ln_g, ln_b, xnb);

    // 2. in_proj: xz = xnb @ Winb^T  (M=16384, N=3072, K=768)
    mfma_gemm<0, bf16_t><<<dim3(3072/128, NR/128), 256, 0, stream>>>(
        xnb, DIMn, Winb, DIMn, xz, 2*DIN, DIMn, 3072, nullptr, nullptr, nullptr);

    // 2b. small padded weights (into now-dead xnb region)
    padxp_kernel<<<(128*DIN + 255)/256, 256, 0, stream>>>(W_xp, Wxpb);
    paddt_kernel<<<(DIN*64  + 255)/256, 256, 0, stream>>>(W_dt, Wdtb);

    // 3. depthwise conv + SiLU -> xc
    conv_silu_kernel<<<(NR*DIN/2)/256, 256, 0, stream>>>(xz, conv_w, conv_b, xc);

    // 4. x_proj: xdbl = xc @ Wxpb^T  (N=80 padded to 128, K=1536)
    mfma_gemm<0, bf16_t><<<dim3(1, NR/128), 256, 0, stream>>>(
        xc, DIN, Wxpb, DIN, xdbl, XPN, DIN, XPN, nullptr, nullptr, nullptr);

    // 5. dt = softplus(xdbl[:, :48] @ Wdtb^T + b_dt)  (K padded 48->64, zeros in W)
    mfma_gemm<1, bf16_t><<<dim3(DIN/128, NR/128), 256, 0, stream>>>(
        xdbl, XPN, Wdtb, 64, dtb, DIN, 64, DIN, b_dt, nullptr, nullptr);

    // 6. scan pass 1: per-chunk (hend, sum dt)
    scan1_kernel<<<Bn*NDG*NCH, 64, 0, stream>>>(dtb, xc, xdbl, A_log, hend, sumdt);

    // 7. scan pass 2: prefix fixup + y + gate -> yg (x_in half of xz)
    scan2_kernel<<<Bn*NDG*NCH, 64, 0, stream>>>(dtb, xc, xdbl, xz, A_log, Dp, hend, sumdt);

    // 8. out_proj + residual: out = mf*(x + yg @ Woutb^T)  (N=768, K=1536)
    mfma_gemm<2, float><<<dim3(DIMn/128, NR/128), 256, 0, stream>>>(
        xz, 2*DIN, Woutb, DIN, out, DIMn, DIN, DIMn, nullptr, x, mask);
}

// Round 7
// 767.053 us; speedup vs baseline: 4.7350x; 1.0615x over previous
//
#include <hip/hip_runtime.h>
#include <math.h>

#define Bn 8
#define Ln 2048
#define DIMn 768
#define DIN 1536           // D_INNER
#define DSTATE 16
#define DTRANK 48
#define XPN 80             // DT_RANK + 2*D_STATE
#define NR (Bn*Ln)         // 16384 rows
#define CH 128             // scan chunk length
#define NCH (Ln/CH)        // 16 chunks
#define NDG4 (DIN/64)      // 24 channel-quadgroups (64 ch per block)
#define TL 64              // scan staging tile (timesteps)

typedef unsigned short bf16_t;
typedef __attribute__((ext_vector_type(8))) short short8;   // 8 bf16 (4 VGPR)
typedef __attribute__((ext_vector_type(4))) float f32x4;

__device__ __forceinline__ float sigf(float v){ return 1.0f/(1.0f+__expf(-v)); }
__device__ __forceinline__ float bf2f(unsigned short u){
    return __uint_as_float(((unsigned int)u) << 16);
}
__device__ __forceinline__ unsigned short f2bf(float f){
    unsigned int x = __float_as_uint(f);
    unsigned int r = (x + 0x7FFFu + ((x >> 16) & 1u)) >> 16;
    return (unsigned short)r;
}

// async global->LDS, 16B per lane; LDS dest = uniform base + lane*16
__device__ __forceinline__ void async_ld16(const bf16_t* g, bf16_t* l) {
    __builtin_amdgcn_global_load_lds(
        (const __attribute__((address_space(1))) unsigned int*)g,
        (__attribute__((address_space(3))) unsigned int*)l,
        16, 0, 0);
}

// quad-lane DPP permute-add (VALU pipe)
template<int CTRL>
__device__ __forceinline__ float dpp_qperm(float x) {
    int v = __builtin_amdgcn_update_dpp(0, __float_as_int(x), CTRL, 0xF, 0xF, true);
    return __int_as_float(v);
}

// ---------------- weight prep ----------------
__global__ __launch_bounds__(256) void f2bf_kernel(
    const float* __restrict__ in, bf16_t* __restrict__ out, int n)
{
    int i = blockIdx.x*256 + threadIdx.x;
    if (i < n) out[i] = f2bf(in[i]);
}
// W_xp (80,1536) -> (128,1536) zero row-padded
__global__ __launch_bounds__(256) void padxp_kernel(
    const float* __restrict__ W, bf16_t* __restrict__ out)
{
    int i = blockIdx.x*256 + threadIdx.x;   // < 128*1536
    int row = i / DIN, col = i % DIN;
    out[i] = (row < XPN) ? f2bf(W[row*DIN + col]) : 0;
}
// W_dt (1536,48) -> (1536,64) zero col-padded
__global__ __launch_bounds__(256) void paddt_kernel(
    const float* __restrict__ W, bf16_t* __restrict__ out)
{
    int i = blockIdx.x*256 + threadIdx.x;   // < 1536*64
    int row = i >> 6, col = i & 63;
    out[i] = (col < DTRANK) ? f2bf(W[row*DTRANK + col]) : 0;
}

// ---------------- LayerNorm + mask -> bf16 ----------------
__global__ __launch_bounds__(256) void ln_kernel(
    const float* __restrict__ x, const int* __restrict__ mask,
    const float* __restrict__ g, const float* __restrict__ bta,
    bf16_t* __restrict__ xn)
{
    int row = blockIdx.x;
    int t = threadIdx.x;
    const float* xr = x + (size_t)row * DIMn;
    float v0 = xr[t], v1 = xr[t+256], v2 = xr[t+512];
    float s  = v0+v1+v2;
    float sq = v0*v0+v1*v1+v2*v2;
    #pragma unroll
    for (int off = 32; off; off >>= 1) {
        s  += __shfl_down(s,  off, 64);
        sq += __shfl_down(sq, off, 64);
    }
    __shared__ float ls[4], lq[4];
    int wave = t >> 6, lane = t & 63;
    if (lane == 0) { ls[wave] = s; lq[wave] = sq; }
    __syncthreads();
    s  = ls[0]+ls[1]+ls[2]+ls[3];
    sq = lq[0]+lq[1]+lq[2]+lq[3];
    float mu  = s * (1.0f/DIMn);
    float var = sq * (1.0f/DIMn) - mu*mu;
    float rstd = rsqrtf(var + 1e-5f);
    float mf = (float)mask[row];
    bf16_t* o = xn + (size_t)row * DIMn;
    o[t]     = f2bf(((v0-mu)*rstd*g[t]     + bta[t])     * mf);
    o[t+256] = f2bf(((v1-mu)*rstd*g[t+256] + bta[t+256]) * mf);
    o[t+512] = f2bf(((v2-mu)*rstd*g[t+512] + bta[t+512]) * mf);
}

// ---------------- LDS-staged bf16 MFMA GEMM: C[M,N] = A[M,K] @ W[N,K]^T ------
// 128x128 tile, BK=32, 4 waves (2x2), fragment-order LDS via global_load_lds.
// EPI: 0 = store bf16, 1 = softplus(acc+bias[n]) bf16, 2 = f32 mf*(resid+acc)
template<int EPI, typename TC>
__global__ __launch_bounds__(256) void mfma_gemm(
    const bf16_t* __restrict__ A, int lda,
    const bf16_t* __restrict__ W, int ldw,
    TC* __restrict__ C, int ldc, int K, int Nb,
    const float* __restrict__ bias,
    const float* __restrict__ resid, const int* __restrict__ mask)
{
    __shared__ __align__(16) bf16_t Als[8*512];
    __shared__ __align__(16) bf16_t Bls[8*512];
    int tid  = threadIdx.x;
    int wave = tid >> 6, lane = tid & 63;
    int mblk = blockIdx.y*128, nblk = blockIdx.x*128;
    int lr16 = lane & 15, kq = lane >> 4;
    int wr = wave >> 1, wc = wave & 1;
    f32x4 acc[4][4] = {};

    for (int k0 = 0; k0 < K; k0 += 32) {
        #pragma unroll
        for (int q = 0; q < 4; q++) {
            int id = wave*4 + q;
            if (id < 8) {
                const bf16_t* g = A + (size_t)(mblk + id*16 + lr16)*lda + k0 + kq*8;
                async_ld16(g, Als + id*512);
            } else {
                const bf16_t* g = W + (size_t)(nblk + (id-8)*16 + lr16)*ldw + k0 + kq*8;
                async_ld16(g, Bls + (id-8)*512);
            }
        }
        __syncthreads();
        short8 a[4], b[4];
        #pragma unroll
        for (int i = 0; i < 4; i++)
            a[i] = *(const short8*)(Als + (wr*4+i)*512 + lane*8);
        #pragma unroll
        for (int i = 0; i < 4; i++)
            b[i] = *(const short8*)(Bls + (wc*4+i)*512 + lane*8);
        #pragma unroll
        for (int mt = 0; mt < 4; mt++)
            #pragma unroll
            for (int nt = 0; nt < 4; nt++)
                acc[mt][nt] = __builtin_amdgcn_mfma_f32_16x16x32_bf16(
                    a[mt], b[nt], acc[mt][nt], 0, 0, 0);
        __syncthreads();
    }

    int m0 = mblk + wr*64, n0 = nblk + wc*64;
    int rb = kq*4;
    #pragma unroll
    for (int mt = 0; mt < 4; mt++) {
        #pragma unroll
        for (int nt = 0; nt < 4; nt++) {
            int col = n0 + nt*16 + lr16;
            if (col >= Nb) continue;
            #pragma unroll
            for (int r = 0; r < 4; r++) {
                int row = m0 + mt*16 + rb + r;
                float v = acc[mt][nt][r];
                if (EPI == 1) {
                    float u = v + bias[col];
                    v = (u > 20.f) ? u : log1pf(__expf(u));
                } else if (EPI == 2) {
                    v = (float)mask[row] * (resid[(size_t)row*ldc + col] + v);
                }
                if constexpr (sizeof(TC) == 2)
                    C[(size_t)row*ldc + col] = f2bf(v);
                else
                    C[(size_t)row*ldc + col] = v;
            }
        }
    }
}

// ---------------- depthwise causal conv (width 4) + SiLU, 2 ch/thread --------
__global__ __launch_bounds__(256) void conv_silu_kernel(
    const bf16_t* __restrict__ xz,
    const float* __restrict__ cw,
    const float* __restrict__ cb,
    bf16_t* __restrict__ xc)
{
    int idx = blockIdx.x*256 + threadIdx.x;       // over NR*DIN/2
    int dh = idx % (DIN/2);
    int r  = idx / (DIN/2);
    int l  = r % Ln;
    int d  = dh*2;
    float4 w0 = *(const float4*)(cw + d*4);
    float4 w1 = *(const float4*)(cw + d*4 + 4);
    float a0 = cb[d], a1 = cb[d+1];
    #pragma unroll
    for (int j = 0; j < 4; j++) {
        int ll = l - 3 + j;
        if (ll >= 0) {
            ushort2 v = *(const ushort2*)(xz + (size_t)(r-3+j)*(2*DIN) + d);
            a0 += bf2f(v.x) * ((const float*)&w0)[j];
            a1 += bf2f(v.y) * ((const float*)&w1)[j];
        }
    }
    ushort2 o; o.x = f2bf(a0*sigf(a0)); o.y = f2bf(a1*sigf(a1));
    *(ushort2*)(xc + (size_t)r*DIN + d) = o;
}

// =============== selective scan, 4 waves/block (64 channels), shared B/C =====
// block = (b, 64-ch group dg4, chunk ch). 256 thr: wave w (16 ch), lane l:
// c16 = l>>2 (channel in wave), g = l&3 (4 states 4g..4g+3).
// LDS tiles: dt/xc/y at channel-stride 72 (row 144B, 16B-aligned, odd-dword).

// ---------------- scan pass 1: per-chunk local end-state ---------------------
__global__ __launch_bounds__(256) void scan1_kernel(
    const bf16_t* __restrict__ dtb,   // (NR, DIN)
    const bf16_t* __restrict__ xcb,   // (NR, DIN)
    const bf16_t* __restrict__ xdbl,  // (NR, 80): cols 48..63 = B
    const float* __restrict__ A_log,
    float* __restrict__ hend,         // per (bdg,ch): 256 lanes x float4
    float* __restrict__ sumdt)        // per (bdg,ch): 64 ch
{
    __shared__ bf16_t dts[TL][72];
    __shared__ bf16_t xcs[TL][72];
    __shared__ float  Bf [TL][16];

    int t = threadIdx.x;
    int w = t >> 6, l = t & 63;
    int c16 = l >> 2, g = l & 3;
    int blk = blockIdx.x;
    int ch  = blk & (NCH-1);
    int bdg = blk >> 4;                 // b*NDG4 + dg4
    int b   = bdg / NDG4, dg4 = bdg % NDG4;
    int d0  = dg4*64;
    int d   = d0 + w*16 + c16;
    int wc  = w*16 + c16;

    float4 a4 = *(const float4*)(A_log + (size_t)d*DSTATE + 4*g);
    float A2[4], h[4] = {0.f,0.f,0.f,0.f};
    A2[0] = -__expf(a4.x)*1.44269504f; A2[1] = -__expf(a4.y)*1.44269504f;
    A2[2] = -__expf(a4.z)*1.44269504f; A2[3] = -__expf(a4.w)*1.44269504f;
    float sdt = 0.f;
    size_t rbase = (size_t)b*Ln + (size_t)ch*CH;

    int tl = t >> 2, qq = t & 3;        // staging role: row tl, 16-ch slice qq
    for (int l0 = 0; l0 < CH; l0 += TL) {
        size_t row = rbase + l0 + tl;
        *(short8*)&dts[tl][qq*16]   = *(const short8*)(dtb + row*DIN + d0 + qq*16);
        *(short8*)&dts[tl][qq*16+8] = *(const short8*)(dtb + row*DIN + d0 + qq*16 + 8);
        *(short8*)&xcs[tl][qq*16]   = *(const short8*)(xcb + row*DIN + d0 + qq*16);
        *(short8*)&xcs[tl][qq*16+8] = *(const short8*)(xcb + row*DIN + d0 + qq*16 + 8);
        if (qq < 2) {   // B: 16 values via 2 threads x 8
            short8 bv = *(const short8*)(xdbl + row*XPN + DTRANK + qq*8);
            #pragma unroll
            for (int j = 0; j < 8; j++)
                Bf[tl][qq*8+j] = bf2f(((unsigned short*)&bv)[j]);
        }
        __syncthreads();
        #pragma unroll 8
        for (int ll = 0; ll < TL; ll++) {
            float dtv = bf2f(dts[ll][wc]);
            float xv  = bf2f(xcs[ll][wc]);
            sdt += dtv;
            float u = dtv * xv;
            float4 Bv = *(const float4*)&Bf[ll][4*g];
            #pragma unroll
            for (int j = 0; j < 4; j++) {
                float e = __builtin_amdgcn_exp2f(dtv * A2[j]);
                h[j] = e*h[j] + u*((const float*)&Bv)[j];
            }
        }
        __syncthreads();
    }
    size_t hbase = ((size_t)(bdg*NCH + ch)*256 + t)*4;
    *(float4*)&hend[hbase] = make_float4(h[0], h[1], h[2], h[3]);
    if (g == 0) sumdt[(size_t)(bdg*NCH + ch)*64 + wc] = sdt;
}

// ---------------- scan pass 2: prefix-fixup + local scan + y + gate ----------
__global__ __launch_bounds__(256) void scan2_kernel(
    const bf16_t* __restrict__ dtb,
    const bf16_t* __restrict__ xcb,
    const bf16_t* __restrict__ xdbl,  // cols 48..63=B, 64..79=C
    bf16_t* __restrict__ xz,          // z read at +DIN, yg write at +0
    const float* __restrict__ A_log,
    const float* __restrict__ Dp,
    const float* __restrict__ hend,
    const float* __restrict__ sumdt)
{
    __shared__ bf16_t dts[TL][72];
    __shared__ bf16_t xcs[TL][72];
    __shared__ bf16_t ybuf[TL][72];
    __shared__ float  Bf [TL][16];
    __shared__ float  Cf [TL][16];

    int t = threadIdx.x;
    int w = t >> 6, l = t & 63;
    int c16 = l >> 2, g = l & 3;
    int blk = blockIdx.x;
    int ch  = blk & (NCH-1);
    int bdg = blk >> 4;
    int b   = bdg / NDG4, dg4 = bdg % NDG4;
    int d0  = dg4*64;
    int d   = d0 + w*16 + c16;
    int wc  = w*16 + c16;

    float4 a4 = *(const float4*)(A_log + (size_t)d*DSTATE + 4*g);
    float A2[4], h[4] = {0.f,0.f,0.f,0.f};
    A2[0] = -__expf(a4.x)*1.44269504f; A2[1] = -__expf(a4.y)*1.44269504f;
    A2[2] = -__expf(a4.z)*1.44269504f; A2[3] = -__expf(a4.w)*1.44269504f;
    float Dv = Dp[d];

    // chunk-prefix from earlier chunks
    for (int cc = 0; cc < ch; cc++) {
        float sd = sumdt[(size_t)(bdg*NCH + cc)*64 + wc];
        float4 he = *(const float4*)&hend[((size_t)(bdg*NCH + cc)*256 + t)*4];
        #pragma unroll
        for (int j = 0; j < 4; j++) {
            float e = __builtin_amdgcn_exp2f(A2[j]*sd);
            h[j] = e*h[j] + ((const float*)&he)[j];
        }
    }

    size_t rbase = (size_t)b*Ln + (size_t)ch*CH;
    int tl = t >> 2, qq = t & 3;
    for (int l0 = 0; l0 < CH; l0 += TL) {
        size_t row = rbase + l0 + tl;
        *(short8*)&dts[tl][qq*16]   = *(const short8*)(dtb + row*DIN + d0 + qq*16);
        *(short8*)&dts[tl][qq*16+8] = *(const short8*)(dtb + row*DIN + d0 + qq*16 + 8);
        *(short8*)&xcs[tl][qq*16]   = *(const short8*)(xcb + row*DIN + d0 + qq*16);
        *(short8*)&xcs[tl][qq*16+8] = *(const short8*)(xcb + row*DIN + d0 + qq*16 + 8);
        {   // B|C: 32 values via 4 threads x 8
            short8 v = *(const short8*)(xdbl + row*XPN + DTRANK + qq*8);
            float* dst = (qq < 2) ? &Bf[tl][qq*8] : &Cf[tl][(qq-2)*8];
            #pragma unroll
            for (int j = 0; j < 8; j++)
                dst[j] = bf2f(((unsigned short*)&v)[j]);
        }
        __syncthreads();
        #pragma unroll 8
        for (int ll = 0; ll < TL; ll++) {
            float dtv = bf2f(dts[ll][wc]);
            float xv  = bf2f(xcs[ll][wc]);
            float u   = dtv * xv;
            float4 Bv = *(const float4*)&Bf[ll][4*g];
            float4 Cv = *(const float4*)&Cf[ll][4*g];
            float p   = 0.f;
            #pragma unroll
            for (int j = 0; j < 4; j++) {
                float e = __builtin_amdgcn_exp2f(dtv * A2[j]);
                h[j] = e*h[j] + u*((const float*)&Bv)[j];
                p = fmaf(h[j], ((const float*)&Cv)[j], p);
            }
            p += dpp_qperm<0xB1>(p);
            p += dpp_qperm<0x4E>(p);
            if (g == 0) ybuf[ll][wc] = f2bf(p + xv*Dv);
        }
        __syncthreads();
        // gate with z, write yg
        {
            const short8* zp0 = (const short8*)(xz + row*(2*DIN) + DIN + d0 + qq*16);
            short8 z0 = zp0[0];
            short8 z1 = *(const short8*)(xz + row*(2*DIN) + DIN + d0 + qq*16 + 8);
            short8 y0 = *(const short8*)&ybuf[tl][qq*16];
            short8 y1 = *(const short8*)&ybuf[tl][qq*16+8];
            short8 o0, o1;
            #pragma unroll
            for (int j = 0; j < 8; j++) {
                float zv = bf2f(((unsigned short*)&z0)[j]);
                ((unsigned short*)&o0)[j] = f2bf(bf2f(((unsigned short*)&y0)[j]) * zv * sigf(zv));
                float zw = bf2f(((unsigned short*)&z1)[j]);
                ((unsigned short*)&o1)[j] = f2bf(bf2f(((unsigned short*)&y1)[j]) * zw * sigf(zw));
            }
            *(short8*)(xz + row*(2*DIN) + d0 + qq*16)     = o0;
            *(short8*)(xz + row*(2*DIN) + d0 + qq*16 + 8) = o1;
        }
        __syncthreads();
    }
}

extern "C" void kernel_launch(void* const* d_in, const int* in_sizes, int n_in,
                              void* d_out, int out_size, void* d_ws, size_t ws_size,
                              hipStream_t stream) {
    const float* x      = (const float*)d_in[0];
    const int*   mask   = (const int*)  d_in[1];
    const float* ln_g   = (const float*)d_in[2];
    const float* ln_b   = (const float*)d_in[3];
    const float* W_in   = (const float*)d_in[4];
    const float* conv_w = (const float*)d_in[5];
    const float* conv_b = (const float*)d_in[6];
    const float* W_xp   = (const float*)d_in[7];
    const float* W_dt   = (const float*)d_in[8];
    const float* b_dt   = (const float*)d_in[9];
    const float* A_log  = (const float*)d_in[10];
    const float* Dp     = (const float*)d_in[11];
    const float* W_out  = (const float*)d_in[12];
    float* out = (float*)d_out;

    char* wsb = (char*)d_ws;
    size_t off = 0;
    bf16_t* xz    = (bf16_t*)(wsb + off); off += (size_t)NR*3072*2;      // 100.7 MB
    bf16_t* xc    = (bf16_t*)(wsb + off); off += (size_t)NR*DIN*2;       //  50.3 MB
    bf16_t* xdbl  = (bf16_t*)(wsb + off); off += (size_t)NR*XPN*2;       //   2.6 MB
    char*   xnbR  = (wsb + off);          off += (size_t)NR*DIMn*2;      //  25.2 MB
    bf16_t* Winb  = (bf16_t*)(wsb + off); off += (size_t)(2*DIN)*DIMn*2; //   4.7 MB
    bf16_t* Woutb = (bf16_t*)(wsb + off); off += (size_t)DIMn*DIN*2;     //   2.4 MB

    bf16_t* xnb   = (bf16_t*)xnbR;
    // aliases inside xnb region (live after in_proj):
    float*  hend  = (float*)xnbR;                          // 3072*1024 f = 12.6 MB
    float*  sumdt = hend + (size_t)3072*1024;              // 3072*64 f   =  0.8 MB
    bf16_t* Wxpb  = (bf16_t*)(sumdt + (size_t)3072*64);    // 128*1536    =  0.4 MB
    bf16_t* Wdtb  = Wxpb + (size_t)128*DIN;                // 1536*64     =  0.2 MB

    bf16_t* dtb = (bf16_t*)d_out;   // dt lives in d_out until final GEMM

    // 0. big-weight conversion
    f2bf_kernel<<<(2*DIN*DIMn + 255)/256, 256, 0, stream>>>(W_in,  Winb,  2*DIN*DIMn);
    f2bf_kernel<<<(DIMn*DIN  + 255)/256, 256, 0, stream>>>(W_out, Woutb, DIMn*DIN);

    // 1. LayerNorm + mask -> xnb
    ln_kernel<<<NR, 256, 0, stream>>>(x, mask, ln_g, ln_b, xnb);

    // 2. in_proj: xz = xnb @ Winb^T  (M=16384, N=3072, K=768)
    mfma_gemm<0, bf16_t><<<dim3(3072/128, NR/128), 256, 0, stream>>>(
        xnb, DIMn, Winb, DIMn, xz, 2*DIN, DIMn, 3072, nullptr, nullptr, nullptr);

    // 2b. small padded weights (into now-dead xnb region)
    padxp_kernel<<<(128*DIN + 255)/256, 256, 0, stream>>>(W_xp, Wxpb);
    paddt_kernel<<<(DIN*64  + 255)/256, 256, 0, stream>>>(W_dt, Wdtb);

    // 3. depthwise conv + SiLU -> xc
    conv_silu_kernel<<<(NR*DIN/2)/256, 256, 0, stream>>>(xz, conv_w, conv_b, xc);

    // 4. x_proj: xdbl = xc @ Wxpb^T  (N=80 padded to 128, K=1536)
    mfma_gemm<0, bf16_t><<<dim3(1, NR/128), 256, 0, stream>>>(
        xc, DIN, Wxpb, DIN, xdbl, XPN, DIN, XPN, nullptr, nullptr, nullptr);

    // 5. dt = softplus(xdbl[:, :48] @ Wdtb^T + b_dt)  (K padded 48->64)
    mfma_gemm<1, bf16_t><<<dim3(DIN/128, NR/128), 256, 0, stream>>>(
        xdbl, XPN, Wdtb, 64, dtb, DIN, 64, DIN, b_dt, nullptr, nullptr);

    // 6. scan pass 1: per-chunk (hend, sum dt)
    scan1_kernel<<<Bn*NDG4*NCH, 256, 0, stream>>>(dtb, xc, xdbl, A_log, hend, sumdt);

    // 7. scan pass 2: prefix fixup + y + gate -> yg (x_in half of xz)
    scan2_kernel<<<Bn*NDG4*NCH, 256, 0, stream>>>(dtb, xc, xdbl, xz, A_log, Dp, hend, sumdt);

    // 8. out_proj + residual: out = mf*(x + yg @ Woutb^T)  (N=768, K=1536)
    mfma_gemm<2, float><<<dim3(DIMn/128, NR/128), 256, 0, stream>>>(
        xz, 2*DIN, Woutb, DIN, out, DIMn, DIN, DIMn, nullptr, x, mask);
}